// Round 11
// baseline (302.646 us; speedup 1.0000x reference)
//
#include <hip/hip_runtime.h>

#define B_ 4096
#define F_ 26
#define L_ 10
#define V_ 100000
#define D_ 128

typedef __attribute__((ext_vector_type(8))) short short8;
typedef __attribute__((ext_vector_type(4))) float f32x4;
typedef unsigned short u16;

// fp32 -> (hi_bf16 << 16) | lo_bf16, both RNE. value ~= hi + lo.
__device__ inline unsigned pack_split(float f) {
    union { float f; unsigned u; } a; a.f = f;
    unsigned r = (a.u + 0x7FFFu + ((a.u >> 16) & 1u)) >> 16;
    union { unsigned u; float f; } hf; hf.u = r << 16;
    float rem = f - hf.f;
    union { float f; unsigned u; } b; b.f = rem;
    unsigned r2 = (b.u + 0x7FFFu + ((b.u >> 16) & 1u)) >> 16;
    return (r << 16) | (r2 & 0xFFFFu);
}
__device__ inline float bf2_to_f(u16 h, u16 l) {
    union { unsigned u; float f; } a; a.u = ((unsigned)h) << 16;
    union { unsigned u; float f; } b; b.u = ((unsigned)l) << 16;
    return a.f + b.f;
}

// ---- merged prep: weights -> transposed hi/lo plane layout [N][2][Kp] ----
__device__ void prep_tile(const float* __restrict__ W, u16* __restrict__ Wt,
                          int K, int N, int Kp, int local)
{
    __shared__ float tile[32][33];
    const int t = threadIdx.x;
    const int tx = t & 31, ty = t >> 5;
    const int nbt = N >> 5;
    const int nb = (local % nbt) << 5, kb = (local / nbt) << 5;
    #pragma unroll
    for (int i = 0; i < 4; ++i) {
        int k = kb + ty + i * 8;
        tile[ty + i * 8][tx] = (k < K) ? W[(size_t)k * N + nb + tx] : 0.f;
    }
    __syncthreads();
    #pragma unroll
    for (int i = 0; i < 4; ++i) {
        int nl = ty + i * 8;
        unsigned u = pack_split(tile[tx][nl]);
        size_t base = (size_t)(nb + nl) * 2 * Kp + kb + tx;
        Wt[base]      = (u16)(u >> 16);
        Wt[base + Kp] = (u16)(u & 0xFFFFu);
    }
}

__global__ __launch_bounds__(256) void prep_all(
    const float* dW0, const float* dW1, const float* dW2,
    const float* oW0, const float* oW1, const float* oW2, const float* oW3,
    u16* dWt0, u16* dWt1, u16* dWt2,
    u16* oWt0, u16* oWt1, u16* oWt2, u16* oWt3,
    const float* dense, u16* densep)
{
    const int bid = blockIdx.x;
    if      (bid < 16)   prep_tile(dW0, dWt0, 13,   512,  32,   bid);
    else if (bid < 144)  prep_tile(dW1, dWt1, 512,  256,  512,  bid - 16);
    else if (bid < 176)  prep_tile(dW2, dWt2, 256,  128,  256,  bid - 144);
    else if (bid < 656)  prep_tile(oW0, oWt0, 479,  1024, 480,  bid - 176);
    else if (bid < 1680) prep_tile(oW1, oWt1, 1024, 1024, 1024, bid - 656);
    else if (bid < 2192) prep_tile(oW2, oWt2, 1024, 512,  1024, bid - 1680);
    else if (bid < 2320) prep_tile(oW3, oWt3, 512,  256,  512,  bid - 2192);
    else {
        int g = (bid - 2320) * 256 + threadIdx.x;   // B*32 slots
        int b = g >> 5, k = g & 31;
        unsigned u = (k < 13) ? pack_split(dense[(size_t)b * 13 + k]) : 0u;
        densep[(size_t)b * 64 + k]      = (u16)(u >> 16);
        densep[(size_t)b * 64 + 32 + k] = (u16)(u & 0xFFFFu);
    }
}

// C = relu(A @ W + bias), bf16x3 MFMA. A:[M][2][Kp] u16 planes,
// Wt:[N][2][Kp], C:[M][2][N]. Tile 128x128, 8 waves (2x4), wave-tile 64x32,
// double-buffered LDS staged via global_load_lds with XOR chunk swizzle;
// fragments are direct ds_read_b128 (NO unpack perms).
__global__ __launch_bounds__(512) void gemm_pl(
    const u16* __restrict__ Ap, const u16* __restrict__ Wt,
    const float* __restrict__ bias, u16* __restrict__ Cp,
    int N, int Kp)
{
    __shared__ __align__(16) u16 Au[2][128 * 64];   // 128 rows x (hi32|lo32)
    __shared__ __align__(16) u16 Bu[2][128 * 64];

    const int t    = threadIdx.x;
    const int lane = t & 63;
    const int w    = t >> 6;
    const int wm   = w >> 2, wn = w & 3;
    const int m0   = blockIdx.y * 128, n0 = blockIdx.x * 128;

    f32x4 acc[4][2];
    const f32x4 zero = {0.f, 0.f, 0.f, 0.f};
    #pragma unroll
    for (int i = 0; i < 4; ++i)
        #pragma unroll
        for (int j = 0; j < 2; ++j) acc[i][j] = zero;

    const u16* Ab = Ap + (size_t)m0 * 2 * Kp;
    const u16* Bb = Wt + (size_t)n0 * 2 * Kp;

    const int g4 = lane >> 4;
    const int rr = lane & 15;

    auto STAGE = [&](int buf, int k0) {
        #pragma unroll
        for (int i = 0; i < 2; ++i) {
            int chunk = t + (i << 9);            // 0..1023 16B chunks
            int row = chunk >> 3, c = chunk & 7;
            int l = c ^ (row & 7);               // logical chunk: p=l>>2, k8=(l&3)*8
            __builtin_amdgcn_global_load_lds(
                (const __attribute__((address_space(1))) u16*)
                    (Ab + (size_t)row * 2 * Kp + (l >> 2) * Kp + k0 + ((l & 3) << 3)),
                &Au[buf][chunk << 3], 16, 0, 0);
        }
        #pragma unroll
        for (int i = 0; i < 2; ++i) {
            int chunk = t + (i << 9);
            int row = chunk >> 3, c = chunk & 7;
            int l = c ^ (row & 7);
            __builtin_amdgcn_global_load_lds(
                (const __attribute__((address_space(1))) u16*)
                    (Bb + (size_t)row * 2 * Kp + (l >> 2) * Kp + k0 + ((l & 3) << 3)),
                &Bu[buf][chunk << 3], 16, 0, 0);
        }
    };

    auto COMPUTE = [&](int buf) {
        const u16* au = Au[buf];
        const u16* bu = Bu[buf];
        short8 bh[2], bl[2];
        #pragma unroll
        for (int tj = 0; tj < 2; ++tj) {
            int r = wn * 32 + tj * 16 + rr;
            int ch = (g4 ^ (r & 7)) << 3;
            int cl = ((4 + g4) ^ (r & 7)) << 3;
            bh[tj] = *reinterpret_cast<const short8*>(&bu[r * 64 + ch]);
            bl[tj] = *reinterpret_cast<const short8*>(&bu[r * 64 + cl]);
        }
        #pragma unroll
        for (int ti = 0; ti < 4; ++ti) {
            int r = wm * 64 + ti * 16 + rr;
            int ch = (g4 ^ (r & 7)) << 3;
            int cl = ((4 + g4) ^ (r & 7)) << 3;
            short8 ah = *reinterpret_cast<const short8*>(&au[r * 64 + ch]);
            short8 al = *reinterpret_cast<const short8*>(&au[r * 64 + cl]);
            #pragma unroll
            for (int tj = 0; tj < 2; ++tj) {
                f32x4 c = acc[ti][tj];
                c = __builtin_amdgcn_mfma_f32_16x16x32_bf16(ah, bh[tj], c, 0, 0, 0);
                c = __builtin_amdgcn_mfma_f32_16x16x32_bf16(ah, bl[tj], c, 0, 0, 0);
                c = __builtin_amdgcn_mfma_f32_16x16x32_bf16(al, bh[tj], c, 0, 0, 0);
                acc[ti][tj] = c;
            }
        }
    };

    const int nt = Kp >> 5;
    STAGE(0, 0);
    __syncthreads();
    int cur = 0;
    for (int ts = 0; ts < nt - 1; ++ts) {
        STAGE(cur ^ 1, (ts + 1) << 5);
        COMPUTE(cur);
        __syncthreads();
        cur ^= 1;
    }
    COMPUTE(cur);

    #pragma unroll
    for (int ti = 0; ti < 4; ++ti) {
        int row = m0 + wm * 64 + ti * 16 + (g4 << 2);
        #pragma unroll
        for (int tj = 0; tj < 2; ++tj) {
            int col = n0 + wn * 32 + tj * 16 + rr;
            float bv = bias[col];
            #pragma unroll
            for (int r = 0; r < 4; ++r) {
                float v = fmaxf(acc[ti][tj][r] + bv, 0.f);
                unsigned u = pack_split(v);
                size_t base = (size_t)(row + r) * 2 * N + col;
                Cp[base]     = (u16)(u >> 16);
                Cp[base + N] = (u16)(u & 0xFFFFu);
            }
        }
    }
}

// 4 samples per block, one wave per sample; 27x27 Gram via bf16x3 MFMA on
// LDS hi/lo planes. Plane-format I/O: x2p [B][2][128], featsp [B][2][480].
__global__ __launch_bounds__(256) void gather_interact_mfma(
    const u16*   __restrict__ x2p,
    const int*   __restrict__ idx_words,
    const float* __restrict__ tables,
    u16*         __restrict__ featsp)
{
    __shared__ unsigned zh[4][32][64];
    __shared__ unsigned zl[4][32][64];
    __shared__ int sidx[4][F_ * L_];
    __shared__ int sstride;

    const int t    = threadIdx.x;
    const int w    = t >> 6;
    const int lane = t & 63;
    const int s    = blockIdx.x * 4 + w;   // sample

    if (t == 0) {
        int st = 2;  // int64: odd (high) words all zero
        for (int ww = 1; ww < 256; ww += 2)
            if (idx_words[ww] != 0) { st = 1; break; }
        sstride = st;
    }
    __syncthreads();
    const int st = sstride;

    for (int q = lane; q < F_ * L_; q += 64) {
        int v = idx_words[((size_t)s * F_ * L_ + q) * st];
        sidx[w][q] = v < 0 ? 0 : (v >= V_ ? V_ - 1 : v);
    }
    // dense row: hi/lo pairs (cols 2*lane, 2*lane+1)
    unsigned hv = *reinterpret_cast<const unsigned*>(x2p + (size_t)s * 256 + 2 * lane);
    unsigned lv = *reinterpret_cast<const unsigned*>(x2p + (size_t)s * 256 + 128 + 2 * lane);
    *reinterpret_cast<unsigned*>(featsp + (size_t)s * 960 + 2 * lane) = hv;
    *reinterpret_cast<unsigned*>(featsp + (size_t)s * 960 + 480 + 2 * lane) = lv;
    if (lane == 0) { featsp[(size_t)s * 960 + 479] = 0; featsp[(size_t)s * 960 + 959] = 0; }
    zh[w][0][lane] = hv;
    zl[w][0][lane] = lv;
    __syncthreads();

    // gather: one float2 per lane per bag row (512B = full row per wave instr)
    for (int f = 0; f < F_; ++f) {
        float2 a = {0.f, 0.f};
        const float* tab = tables + (size_t)f * V_ * D_;
        #pragma unroll
        for (int l = 0; l < L_; ++l) {
            int idx = sidx[w][f * L_ + l];
            float2 v = *reinterpret_cast<const float2*>(tab + (size_t)idx * D_ + 2 * lane);
            a.x += v.x; a.y += v.y;
        }
        unsigned px = pack_split(a.x), py = pack_split(a.y);
        int r  = f + 1;
        int dw = (((lane >> 2) ^ (r & 7)) << 2) + (lane & 3);  // chunk-swizzled dword
        zh[w][r][dw] = (px >> 16) | (py & 0xFFFF0000u);
        zl[w][r][dw] = (px & 0xFFFFu) | (py << 16);
    }
    __syncthreads();

    const int g4 = lane >> 4;
    const int rr = lane & 15;
    f32x4 acc[2][2];
    const f32x4 zero = {0.f, 0.f, 0.f, 0.f};
    acc[0][0] = zero; acc[0][1] = zero; acc[1][0] = zero; acc[1][1] = zero;

    #pragma unroll
    for (int ks = 0; ks < 4; ++ks) {
        short8 h[2], lo[2];
        #pragma unroll
        for (int mi = 0; mi < 2; ++mi) {
            int r = mi * 16 + rr;
            int c = (ks * 4 + g4) ^ (r & 7);
            h[mi]  = *reinterpret_cast<const short8*>(&zh[w][r][c << 2]);
            lo[mi] = *reinterpret_cast<const short8*>(&zl[w][r][c << 2]);
        }
        #pragma unroll
        for (int mi = 0; mi < 2; ++mi)
            #pragma unroll
            for (int nj = 0; nj < 2; ++nj) {
                f32x4 c = acc[mi][nj];
                c = __builtin_amdgcn_mfma_f32_16x16x32_bf16(h[mi],  h[nj],  c, 0, 0, 0);
                c = __builtin_amdgcn_mfma_f32_16x16x32_bf16(h[mi],  lo[nj], c, 0, 0, 0);
                c = __builtin_amdgcn_mfma_f32_16x16x32_bf16(lo[mi], h[nj],  c, 0, 0, 0);
                acc[mi][nj] = c;
            }
    }

    #pragma unroll
    for (int mi = 0; mi < 2; ++mi) {
        #pragma unroll
        for (int nj = 0; nj < 2; ++nj) {
            #pragma unroll
            for (int r = 0; r < 4; ++r) {
                int i = mi * 16 + g4 * 4 + r;
                int j = nj * 16 + rr;
                if (i < j && j <= 26) {
                    int p = i * 26 - (i * (i - 1)) / 2 + (j - i - 1);
                    unsigned u = pack_split(acc[mi][nj][r]);
                    featsp[(size_t)s * 960 + 128 + p]       = (u16)(u >> 16);
                    featsp[(size_t)s * 960 + 480 + 128 + p] = (u16)(u & 0xFFFFu);
                }
            }
        }
    }
}

// logits[b] = dot(y3[b,:256], w) + bias; y3 plane layout [B][2][256]
__global__ __launch_bounds__(256) void final_dot(
    const u16* __restrict__ yp, const float* __restrict__ w,
    const float* __restrict__ bias, float* __restrict__ out)
{
    const int wave = threadIdx.x >> 6;
    const int lane = threadIdx.x & 63;
    const int b = blockIdx.x * 4 + wave;
    const u16* row = yp + (size_t)b * 512;
    ushort4 uh = *reinterpret_cast<const ushort4*>(row + 4 * lane);
    ushort4 ul = *reinterpret_cast<const ushort4*>(row + 256 + 4 * lane);
    float4 wv = *reinterpret_cast<const float4*>(&w[lane * 4]);
    float s = bf2_to_f(uh.x, ul.x) * wv.x + bf2_to_f(uh.y, ul.y) * wv.y +
              bf2_to_f(uh.z, ul.z) * wv.z + bf2_to_f(uh.w, ul.w) * wv.w;
    #pragma unroll
    for (int off = 32; off; off >>= 1) s += __shfl_xor(s, off);
    if (lane == 0) out[b] = s + bias[0];
}

extern "C" void kernel_launch(void* const* d_in, const int* in_sizes, int n_in,
                              void* d_out, int out_size, void* d_ws, size_t ws_size,
                              hipStream_t stream)
{
    const float* dense   = (const float*)d_in[0];
    const int*   indices = (const int*)  d_in[1];
    const float* tables  = (const float*)d_in[2];
    const float* dW0 = (const float*)d_in[3];  const float* db0 = (const float*)d_in[4];
    const float* dW1 = (const float*)d_in[5];  const float* db1 = (const float*)d_in[6];
    const float* dW2 = (const float*)d_in[7];  const float* db2 = (const float*)d_in[8];
    const float* oW0 = (const float*)d_in[9];  const float* ob0 = (const float*)d_in[10];
    const float* oW1 = (const float*)d_in[11]; const float* ob1 = (const float*)d_in[12];
    const float* oW2 = (const float*)d_in[13]; const float* ob2 = (const float*)d_in[14];
    const float* oW3 = (const float*)d_in[15]; const float* ob3 = (const float*)d_in[16];
    const float* oW4 = (const float*)d_in[17]; const float* ob4 = (const float*)d_in[18];
    float* out = (float*)d_out;

    // Same byte layout as rounds 5-10 (uint offsets), reinterpreted as u16
    // hi/lo plane arrays ([row][2][Kp] u16 == [row][Kp] uint in bytes).
    unsigned* wsu = (unsigned*)d_ws;
    u16* dWt0 = (u16*)(wsu + 0);          // [512][2][32]
    u16* dWt1 = (u16*)(wsu + 16384);      // [256][2][512]
    u16* dWt2 = (u16*)(wsu + 147456);     // [128][2][256]
    u16* oWt0 = (u16*)(wsu + 180224);     // [1024][2][480]
    u16* oWt1 = (u16*)(wsu + 671744);     // [1024][2][1024]
    u16* oWt2 = (u16*)(wsu + 1720320);    // [512][2][1024]
    u16* oWt3 = (u16*)(wsu + 2244608);    // [256][2][512]
    u16* densep = (u16*)(wsu + 2375680);  // [4096][2][32]
    u16* x2p    = (u16*)(wsu + 2506752);  // [4096][2][128]
    u16* featsp = (u16*)(wsu + 3031040);  // [4096][2][480]
    u16* x0p    = (u16*)(wsu + 5000000);  // [4096][2][512]
    u16* x1p    = (u16*)(wsu + 7097152);  // [4096][2][256]
    u16* y0p    = (u16*)(wsu + 5000000);  // [4096][2][1024] (x0p/x1p dead)
    u16* y1p    = (u16*)(wsu + 9194304);  // [4096][2][1024]
    u16* y2p    = (u16*)(wsu + 2506752);  // [4096][2][512]  (x2p/featsp dead)
    u16* y3p    = (u16*)(wsu + 5000000);  // [4096][2][256]  (y0p dead)
    // high water 53.6 MB

    prep_all<<<2832, 256, 0, stream>>>(dW0, dW1, dW2, oW0, oW1, oW2, oW3,
                                       dWt0, dWt1, dWt2, oWt0, oWt1, oWt2, oWt3,
                                       dense, densep);

    // bottom MLP (round-8 launch config: 8 waves, 2-D grid)
    gemm_pl<<<dim3(4, 32), 512, 0, stream>>>(densep, dWt0, db0, x0p, 512, 32);
    gemm_pl<<<dim3(2, 32), 512, 0, stream>>>(x0p,    dWt1, db1, x1p, 256, 512);
    gemm_pl<<<dim3(1, 32), 512, 0, stream>>>(x1p,    dWt2, db2, x2p, 128, 256);

    gather_interact_mfma<<<B_ / 4, 256, 0, stream>>>(x2p, indices, tables, featsp);

    // over MLP
    gemm_pl<<<dim3(8, 32), 512, 0, stream>>>(featsp, oWt0, ob0, y0p, 1024, 480);
    gemm_pl<<<dim3(8, 32), 512, 0, stream>>>(y0p,    oWt1, ob1, y1p, 1024, 1024);
    gemm_pl<<<dim3(4, 32), 512, 0, stream>>>(y1p,    oWt2, ob2, y2p, 512, 1024);
    gemm_pl<<<dim3(2, 32), 512, 0, stream>>>(y2p,    oWt3, ob3, y3p, 256, 512);

    final_dot<<<B_ / 4, 256, 0, stream>>>(y3p, oW4, ob4, out);
}

// Round 12
// 301.425 us; speedup vs baseline: 1.0041x; 1.0041x over previous
//
#include <hip/hip_runtime.h>

#define B_ 4096
#define F_ 26
#define L_ 10
#define V_ 100000
#define D_ 128

typedef __attribute__((ext_vector_type(8))) short short8;
typedef __attribute__((ext_vector_type(4))) float f32x4;

// fp32 -> packed (hi_bf16 << 16) | lo_bf16, both RNE. value ~= hi + lo.
__device__ inline unsigned pack_split(float f) {
    union { float f; unsigned u; } a; a.f = f;
    unsigned r = (a.u + 0x7FFFu + ((a.u >> 16) & 1u)) >> 16;
    union { unsigned u; float f; } hf; hf.u = r << 16;
    float rem = f - hf.f;
    union { float f; unsigned u; } b; b.f = rem;
    unsigned r2 = (b.u + 0x7FFFu + ((b.u >> 16) & 1u)) >> 16;
    return (r << 16) | (r2 & 0xFFFFu);
}
__device__ inline float unpack_f(unsigned u) {
    union { unsigned u; float f; } h; h.u = u & 0xFFFF0000u;
    union { unsigned u; float f; } l; l.u = u << 16;
    return h.f + l.f;
}

// ---- merged prep: 7 weight transposes + dense pad in ONE launch ----
__device__ void prep_tile(const float* __restrict__ W, unsigned* __restrict__ Wt,
                          int K, int N, int Kp, int local)
{
    __shared__ float tile[32][33];
    const int t = threadIdx.x;
    const int tx = t & 31, ty = t >> 5;
    const int nbt = N >> 5;
    const int nb = (local % nbt) << 5, kb = (local / nbt) << 5;
    #pragma unroll
    for (int i = 0; i < 4; ++i) {
        int k = kb + ty + i * 8;
        tile[ty + i * 8][tx] = (k < K) ? W[(size_t)k * N + nb + tx] : 0.f;
    }
    __syncthreads();
    #pragma unroll
    for (int i = 0; i < 4; ++i) {
        int nl = ty + i * 8;
        Wt[(size_t)(nb + nl) * Kp + kb + tx] = pack_split(tile[tx][nl]);
    }
}

__global__ __launch_bounds__(256) void prep_all(
    const float* dW0, const float* dW1, const float* dW2,
    const float* oW0, const float* oW1, const float* oW2, const float* oW3,
    unsigned* dWt0, unsigned* dWt1, unsigned* dWt2,
    unsigned* oWt0, unsigned* oWt1, unsigned* oWt2, unsigned* oWt3,
    const float* dense, unsigned* densep)
{
    const int bid = blockIdx.x;
    if      (bid < 16)   prep_tile(dW0, dWt0, 13,   512,  32,   bid);
    else if (bid < 144)  prep_tile(dW1, dWt1, 512,  256,  512,  bid - 16);
    else if (bid < 176)  prep_tile(dW2, dWt2, 256,  128,  256,  bid - 144);
    else if (bid < 656)  prep_tile(oW0, oWt0, 479,  1024, 480,  bid - 176);
    else if (bid < 1680) prep_tile(oW1, oWt1, 1024, 1024, 1024, bid - 656);
    else if (bid < 2192) prep_tile(oW2, oWt2, 1024, 512,  1024, bid - 1680);
    else if (bid < 2320) prep_tile(oW3, oWt3, 512,  256,  512,  bid - 2192);
    else {
        int g = (bid - 2320) * 256 + threadIdx.x;   // B*32 slots
        int b = g >> 5, k = g & 31;
        densep[g] = (k < 13) ? pack_split(dense[(size_t)b * 13 + k]) : 0u;
    }
}

// C = relu(A @ W + bias), bf16x3 MFMA, 8 waves (2x4), wave-tile 64x32.
// Counted-vmcnt pipeline (T4): A triple-buffered (prefetch distance 2),
// B double-buffered (distance 1); raw s_barrier + s_waitcnt vmcnt(2) in the
// main loop (per thread: 2 A-loads + 2 B-loads per stage; at the wait,
// outstanding = [A(t) B(t) A(t+1)] <= 6 -> vmcnt(2) retires tile t's A+B,
// leaves A(t+1) in flight ACROSS the barrier). vmcnt(0) only on last iter.
__global__ __launch_bounds__(512) void gemm8(
    const unsigned* __restrict__ Ap, const unsigned* __restrict__ Wt,
    const float* __restrict__ bias, unsigned* __restrict__ Cp,
    int N, int Kp)
{
    __shared__ __align__(16) unsigned Au[3][128 * 32];   // 48 KB
    __shared__ __align__(16) unsigned Bu[2][128 * 32];   // 32 KB -> 80 KB total

    const int t    = threadIdx.x;
    const int lane = t & 63;
    const int w    = t >> 6;
    const int wm   = w >> 2, wn = w & 3;
    const int m0   = blockIdx.y * 128, n0 = blockIdx.x * 128;

    f32x4 acc[4][2];
    const f32x4 zero = {0.f, 0.f, 0.f, 0.f};
    #pragma unroll
    for (int i = 0; i < 4; ++i)
        #pragma unroll
        for (int j = 0; j < 2; ++j) acc[i][j] = zero;

    const unsigned* Ab = Ap + (size_t)m0 * Kp;
    const unsigned* Bb = Wt + (size_t)n0 * Kp;

    const int g4 = lane >> 4;
    const int rr = lane & 15;

    auto STAGE_A = [&](int buf, int kt) {
        int k0 = kt << 5;
        #pragma unroll
        for (int i = 0; i < 2; ++i) {
            int chunk = t + (i << 9);
            int row = chunk >> 3, ch = chunk & 7;
            int sch = ch ^ (row & 7);
            __builtin_amdgcn_global_load_lds(
                (const __attribute__((address_space(1))) unsigned*)(Ab + (size_t)row * Kp + k0 + (sch << 2)),
                &Au[buf][chunk << 2], 16, 0, 0);
        }
    };
    auto STAGE_B = [&](int buf, int kt) {
        int k0 = kt << 5;
        #pragma unroll
        for (int i = 0; i < 2; ++i) {
            int chunk = t + (i << 9);
            int row = chunk >> 3, ch = chunk & 7;
            int sch = ch ^ (row & 7);
            __builtin_amdgcn_global_load_lds(
                (const __attribute__((address_space(1))) unsigned*)(Bb + (size_t)row * Kp + k0 + (sch << 2)),
                &Bu[buf][chunk << 2], 16, 0, 0);
        }
    };

    auto COMPUTE = [&](int abuf, int bbuf) {
        const unsigned* au = Au[abuf];
        const unsigned* bu = Bu[bbuf];
        short8 bh[2], bl[2];
        #pragma unroll
        for (int tj = 0; tj < 2; ++tj) {
            int r = wn * 32 + tj * 16 + rr;
            int c0 = (2 * g4) ^ (r & 7), c1 = (2 * g4 + 1) ^ (r & 7);
            uint4 p = *reinterpret_cast<const uint4*>(&bu[r * 32 + (c0 << 2)]);
            uint4 q = *reinterpret_cast<const uint4*>(&bu[r * 32 + (c1 << 2)]);
            union { short8 s; uint4 u; } H, L;
            H.u.x = __builtin_amdgcn_perm(p.y, p.x, 0x07060302u);
            L.u.x = __builtin_amdgcn_perm(p.y, p.x, 0x05040100u);
            H.u.y = __builtin_amdgcn_perm(p.w, p.z, 0x07060302u);
            L.u.y = __builtin_amdgcn_perm(p.w, p.z, 0x05040100u);
            H.u.z = __builtin_amdgcn_perm(q.y, q.x, 0x07060302u);
            L.u.z = __builtin_amdgcn_perm(q.y, q.x, 0x05040100u);
            H.u.w = __builtin_amdgcn_perm(q.w, q.z, 0x07060302u);
            L.u.w = __builtin_amdgcn_perm(q.w, q.z, 0x05040100u);
            bh[tj] = H.s; bl[tj] = L.s;
        }
        #pragma unroll
        for (int ti = 0; ti < 4; ++ti) {
            int r = wm * 64 + ti * 16 + rr;
            int c0 = (2 * g4) ^ (r & 7), c1 = (2 * g4 + 1) ^ (r & 7);
            uint4 p = *reinterpret_cast<const uint4*>(&au[r * 32 + (c0 << 2)]);
            uint4 q = *reinterpret_cast<const uint4*>(&au[r * 32 + (c1 << 2)]);
            union { short8 s; uint4 u; } H, L;
            H.u.x = __builtin_amdgcn_perm(p.y, p.x, 0x07060302u);
            L.u.x = __builtin_amdgcn_perm(p.y, p.x, 0x05040100u);
            H.u.y = __builtin_amdgcn_perm(p.w, p.z, 0x07060302u);
            L.u.y = __builtin_amdgcn_perm(p.w, p.z, 0x05040100u);
            H.u.z = __builtin_amdgcn_perm(q.y, q.x, 0x07060302u);
            L.u.z = __builtin_amdgcn_perm(q.y, q.x, 0x05040100u);
            H.u.w = __builtin_amdgcn_perm(q.w, q.z, 0x07060302u);
            L.u.w = __builtin_amdgcn_perm(q.w, q.z, 0x05040100u);
            short8 ah = H.s, al = L.s;
            #pragma unroll
            for (int tj = 0; tj < 2; ++tj) {
                f32x4 c = acc[ti][tj];
                c = __builtin_amdgcn_mfma_f32_16x16x32_bf16(ah, bh[tj], c, 0, 0, 0);
                c = __builtin_amdgcn_mfma_f32_16x16x32_bf16(ah, bl[tj], c, 0, 0, 0);
                c = __builtin_amdgcn_mfma_f32_16x16x32_bf16(al, bh[tj], c, 0, 0, 0);
                acc[ti][tj] = c;
            }
        }
    };

    const int nt = Kp >> 5;
    // prologue issue order: A(0), B(0), A(1)
    STAGE_A(0, 0);
    STAGE_B(0, 0);
    if (nt > 1) STAGE_A(1, 1);

    for (int ts = 0; ts < nt; ++ts) {
        if (ts < nt - 1) asm volatile("s_waitcnt vmcnt(2)" ::: "memory");
        else             asm volatile("s_waitcnt vmcnt(0)" ::: "memory");
        __builtin_amdgcn_s_barrier();
        __builtin_amdgcn_sched_barrier(0);
        if (ts + 1 < nt) STAGE_B((ts + 1) & 1, ts + 1);   // overwrites B(ts-1): all waves done
        if (ts + 2 < nt) STAGE_A((ts + 2) % 3, ts + 2);   // overwrites A(ts-1): all waves done
        COMPUTE(ts % 3, ts & 1);
    }

    #pragma unroll
    for (int ti = 0; ti < 4; ++ti) {
        int row = m0 + wm * 64 + ti * 16 + (g4 << 2);
        #pragma unroll
        for (int tj = 0; tj < 2; ++tj) {
            int col = n0 + wn * 32 + tj * 16 + rr;
            float bv = bias[col];
            #pragma unroll
            for (int r = 0; r < 4; ++r) {
                float v = fmaxf(acc[ti][tj][r] + bv, 0.f);
                Cp[(size_t)(row + r) * N + col] = pack_split(v);
            }
        }
    }
}

// 4 samples per block, one wave per sample. Gather bags into LDS hi/lo
// bf16 planes (XOR chunk-swizzled), then 27x27 Gram matrix via bf16x3 MFMA.
__global__ __launch_bounds__(256) void gather_interact_mfma(
    const unsigned* __restrict__ x2p,      // [B,128] packed
    const int*      __restrict__ idx_words,
    const float*    __restrict__ tables,   // [26,100000,128] fp32
    unsigned*       __restrict__ featsp)   // [B,480] packed
{
    __shared__ unsigned zh[4][32][64];
    __shared__ unsigned zl[4][32][64];
    __shared__ int sidx[4][F_ * L_];
    __shared__ int sstride;

    const int t    = threadIdx.x;
    const int w    = t >> 6;
    const int lane = t & 63;
    const int s    = blockIdx.x * 4 + w;   // sample

    if (t == 0) {
        int st = 2;  // int64: odd (high) words all zero
        for (int ww = 1; ww < 256; ww += 2)
            if (idx_words[ww] != 0) { st = 1; break; }
        sstride = st;
    }
    __syncthreads();
    const int st = sstride;

    for (int q = lane; q < F_ * L_; q += 64) {
        int v = idx_words[((size_t)s * F_ * L_ + q) * st];
        sidx[w][q] = v < 0 ? 0 : (v >= V_ ? V_ - 1 : v);
    }
    uint2 xv = *reinterpret_cast<const uint2*>(x2p + (size_t)s * 128 + 2 * lane);
    *reinterpret_cast<uint2*>(featsp + (size_t)s * 480 + 2 * lane) = xv;
    if (lane == 0) featsp[(size_t)s * 480 + 479] = 0u;
    zh[w][0][lane] = (xv.x >> 16) | (xv.y & 0xFFFF0000u);
    zl[w][0][lane] = (xv.x & 0xFFFFu) | (xv.y << 16);
    __syncthreads();

    // gather: one float2 per lane per bag row (512B = full row per wave instr)
    for (int f = 0; f < F_; ++f) {
        float2 a = {0.f, 0.f};
        const float* tab = tables + (size_t)f * V_ * D_;
        #pragma unroll
        for (int l = 0; l < L_; ++l) {
            int idx = sidx[w][f * L_ + l];
            float2 v = *reinterpret_cast<const float2*>(tab + (size_t)idx * D_ + 2 * lane);
            a.x += v.x; a.y += v.y;
        }
        unsigned px = pack_split(a.x), py = pack_split(a.y);
        int r  = f + 1;
        int dw = (((lane >> 2) ^ (r & 7)) << 2) + (lane & 3);  // chunk-swizzled dword
        zh[w][r][dw] = (px >> 16) | (py & 0xFFFF0000u);
        zl[w][r][dw] = (px & 0xFFFFu) | (py << 16);
    }
    __syncthreads();

    const int g4 = lane >> 4;
    const int rr = lane & 15;
    f32x4 acc[2][2];
    const f32x4 zero = {0.f, 0.f, 0.f, 0.f};
    acc[0][0] = zero; acc[0][1] = zero; acc[1][0] = zero; acc[1][1] = zero;

    #pragma unroll
    for (int ks = 0; ks < 4; ++ks) {
        short8 h[2], lo[2];
        #pragma unroll
        for (int mi = 0; mi < 2; ++mi) {
            int r = mi * 16 + rr;
            int c = (ks * 4 + g4) ^ (r & 7);
            h[mi]  = *reinterpret_cast<const short8*>(&zh[w][r][c << 2]);
            lo[mi] = *reinterpret_cast<const short8*>(&zl[w][r][c << 2]);
        }
        #pragma unroll
        for (int mi = 0; mi < 2; ++mi)
            #pragma unroll
            for (int nj = 0; nj < 2; ++nj) {
                f32x4 c = acc[mi][nj];
                c = __builtin_amdgcn_mfma_f32_16x16x32_bf16(h[mi],  h[nj],  c, 0, 0, 0);
                c = __builtin_amdgcn_mfma_f32_16x16x32_bf16(h[mi],  lo[nj], c, 0, 0, 0);
                c = __builtin_amdgcn_mfma_f32_16x16x32_bf16(lo[mi], h[nj],  c, 0, 0, 0);
                acc[mi][nj] = c;
            }
    }

    #pragma unroll
    for (int mi = 0; mi < 2; ++mi) {
        #pragma unroll
        for (int nj = 0; nj < 2; ++nj) {
            #pragma unroll
            for (int r = 0; r < 4; ++r) {
                int i = mi * 16 + g4 * 4 + r;
                int j = nj * 16 + rr;
                if (i < j && j <= 26) {
                    int p = i * 26 - (i * (i - 1)) / 2 + (j - i - 1);
                    featsp[(size_t)s * 480 + 128 + p] = pack_split(acc[mi][nj][r]);
                }
            }
        }
    }
}

// logits[b] = dot(unpack(y3p[b,:256]), w) + bias
__global__ __launch_bounds__(256) void final_dot(
    const unsigned* __restrict__ yp, const float* __restrict__ w,
    const float* __restrict__ bias, float* __restrict__ out)
{
    const int wave = threadIdx.x >> 6;
    const int lane = threadIdx.x & 63;
    const int b = blockIdx.x * 4 + wave;
    uint4 u = *reinterpret_cast<const uint4*>(yp + (size_t)b * 256 + lane * 4);
    float4 wv = *reinterpret_cast<const float4*>(&w[lane * 4]);
    float s = unpack_f(u.x) * wv.x + unpack_f(u.y) * wv.y +
              unpack_f(u.z) * wv.z + unpack_f(u.w) * wv.w;
    #pragma unroll
    for (int off = 32; off; off >>= 1) s += __shfl_xor(s, off);
    if (lane == 0) out[b] = s + bias[0];
}

extern "C" void kernel_launch(void* const* d_in, const int* in_sizes, int n_in,
                              void* d_out, int out_size, void* d_ws, size_t ws_size,
                              hipStream_t stream)
{
    const float* dense   = (const float*)d_in[0];
    const int*   indices = (const int*)  d_in[1];
    const float* tables  = (const float*)d_in[2];
    const float* dW0 = (const float*)d_in[3];  const float* db0 = (const float*)d_in[4];
    const float* dW1 = (const float*)d_in[5];  const float* db1 = (const float*)d_in[6];
    const float* dW2 = (const float*)d_in[7];  const float* db2 = (const float*)d_in[8];
    const float* oW0 = (const float*)d_in[9];  const float* ob0 = (const float*)d_in[10];
    const float* oW1 = (const float*)d_in[11]; const float* ob1 = (const float*)d_in[12];
    const float* oW2 = (const float*)d_in[13]; const float* ob2 = (const float*)d_in[14];
    const float* oW3 = (const float*)d_in[15]; const float* ob3 = (const float*)d_in[16];
    const float* oW4 = (const float*)d_in[17]; const float* ob4 = (const float*)d_in[18];
    float* out = (float*)d_out;

    unsigned* wsu = (unsigned*)d_ws;
    unsigned* dWt0 = wsu + 0;          // [512][32]
    unsigned* dWt1 = wsu + 16384;      // [256][512]
    unsigned* dWt2 = wsu + 147456;     // [128][256]
    unsigned* oWt0 = wsu + 180224;     // [1024][480]
    unsigned* oWt1 = wsu + 671744;     // [1024][1024]
    unsigned* oWt2 = wsu + 1720320;    // [512][1024]
    unsigned* oWt3 = wsu + 2244608;    // [256][512]
    unsigned* densep = wsu + 2375680;  // [4096][32]
    unsigned* x2p    = wsu + 2506752;  // [4096][128]
    unsigned* featsp = wsu + 3031040;  // [4096][480]
    unsigned* x0p    = wsu + 5000000;  // [4096][512]
    unsigned* x1p    = wsu + 7097152;  // [4096][256]
    unsigned* y0p    = wsu + 5000000;  // [4096][1024] (x0p/x1p dead)
    unsigned* y1p    = wsu + 9194304;  // [4096][1024]
    unsigned* y2p    = wsu + 2506752;  // [4096][512]  (x2p/featsp dead)
    unsigned* y3p    = wsu + 5000000;  // [4096][256]  (y0p dead)
    // high water 53.6 MB

    prep_all<<<2832, 256, 0, stream>>>(dW0, dW1, dW2, oW0, oW1, oW2, oW3,
                                       dWt0, dWt1, dWt2, oWt0, oWt1, oWt2, oWt3,
                                       dense, densep);

    gemm8<<<dim3(4, 32), 512, 0, stream>>>(densep, dWt0, db0, x0p, 512, 32);
    gemm8<<<dim3(2, 32), 512, 0, stream>>>(x0p,    dWt1, db1, x1p, 256, 512);
    gemm8<<<dim3(1, 32), 512, 0, stream>>>(x1p,    dWt2, db2, x2p, 128, 256);

    gather_interact_mfma<<<B_ / 4, 256, 0, stream>>>(x2p, indices, tables, featsp);

    gemm8<<<dim3(8, 32), 512, 0, stream>>>(featsp, oWt0, ob0, y0p, 1024, 480);
    gemm8<<<dim3(8, 32), 512, 0, stream>>>(y0p,    oWt1, ob1, y1p, 1024, 1024);
    gemm8<<<dim3(4, 32), 512, 0, stream>>>(y1p,    oWt2, ob2, y2p, 512, 1024);
    gemm8<<<dim3(2, 32), 512, 0, stream>>>(y2p,    oWt3, ob3, y3p, 256, 512);

    final_dot<<<B_ / 4, 256, 0, stream>>>(y3p, oW4, ob4, out);
}

// Round 13
// 287.274 us; speedup vs baseline: 1.0535x; 1.0493x over previous
//
#include <hip/hip_runtime.h>

#define B_ 4096
#define F_ 26
#define L_ 10
#define V_ 100000
#define D_ 128

typedef __attribute__((ext_vector_type(8))) short short8;
typedef __attribute__((ext_vector_type(4))) float f32x4;

// fp32 -> packed (hi_bf16 << 16) | lo_bf16, both RNE. value ~= hi + lo.
__device__ inline unsigned pack_split(float f) {
    union { float f; unsigned u; } a; a.f = f;
    unsigned r = (a.u + 0x7FFFu + ((a.u >> 16) & 1u)) >> 16;
    union { unsigned u; float f; } hf; hf.u = r << 16;
    float rem = f - hf.f;
    union { float f; unsigned u; } b; b.f = rem;
    unsigned r2 = (b.u + 0x7FFFu + ((b.u >> 16) & 1u)) >> 16;
    return (r << 16) | (r2 & 0xFFFFu);
}
__device__ inline float unpack_f(unsigned u) {
    union { unsigned u; float f; } h; h.u = u & 0xFFFF0000u;
    union { unsigned u; float f; } l; l.u = u << 16;
    return h.f + l.f;
}

// ---- merged prep: 7 weight transposes + dense pad in ONE launch ----
__device__ void prep_tile(const float* __restrict__ W, unsigned* __restrict__ Wt,
                          int K, int N, int Kp, int local)
{
    __shared__ float tile[32][33];
    const int t = threadIdx.x;
    const int tx = t & 31, ty = t >> 5;
    const int nbt = N >> 5;
    const int nb = (local % nbt) << 5, kb = (local / nbt) << 5;
    #pragma unroll
    for (int i = 0; i < 4; ++i) {
        int k = kb + ty + i * 8;
        tile[ty + i * 8][tx] = (k < K) ? W[(size_t)k * N + nb + tx] : 0.f;
    }
    __syncthreads();
    #pragma unroll
    for (int i = 0; i < 4; ++i) {
        int nl = ty + i * 8;
        Wt[(size_t)(nb + nl) * Kp + kb + tx] = pack_split(tile[tx][nl]);
    }
}

__global__ __launch_bounds__(256) void prep_all(
    const float* dW0, const float* dW1, const float* dW2,
    const float* oW0, const float* oW1, const float* oW2, const float* oW3,
    unsigned* dWt0, unsigned* dWt1, unsigned* dWt2,
    unsigned* oWt0, unsigned* oWt1, unsigned* oWt2, unsigned* oWt3,
    const float* dense, unsigned* densep)
{
    const int bid = blockIdx.x;
    if      (bid < 16)   prep_tile(dW0, dWt0, 13,   512,  32,   bid);
    else if (bid < 144)  prep_tile(dW1, dWt1, 512,  256,  512,  bid - 16);
    else if (bid < 176)  prep_tile(dW2, dWt2, 256,  128,  256,  bid - 144);
    else if (bid < 656)  prep_tile(oW0, oWt0, 479,  1024, 480,  bid - 176);
    else if (bid < 1680) prep_tile(oW1, oWt1, 1024, 1024, 1024, bid - 656);
    else if (bid < 2192) prep_tile(oW2, oWt2, 1024, 512,  1024, bid - 1680);
    else if (bid < 2320) prep_tile(oW3, oWt3, 512,  256,  512,  bid - 2192);
    else {
        int g = (bid - 2320) * 256 + threadIdx.x;   // B*32 slots
        int b = g >> 5, k = g & 31;
        densep[g] = (k < 13) ? pack_split(dense[(size_t)b * 13 + k]) : 0u;
    }
}

// C = relu(A @ W + bias), bf16x3 MFMA, 8 waves (2x4), wave-tile 64x32,
// double-buffered LDS (exact round-8 structure: best measured).
__global__ __launch_bounds__(512) void gemm8(
    const unsigned* __restrict__ Ap, const unsigned* __restrict__ Wt,
    const float* __restrict__ bias, unsigned* __restrict__ Cp,
    int N, int Kp)
{
    __shared__ __align__(16) unsigned Au[2][128 * 32];
    __shared__ __align__(16) unsigned Bu[2][128 * 32];

    const int t    = threadIdx.x;
    const int lane = t & 63;
    const int w    = t >> 6;
    const int wm   = w >> 2, wn = w & 3;
    const int m0   = blockIdx.y * 128, n0 = blockIdx.x * 128;

    f32x4 acc[4][2];
    const f32x4 zero = {0.f, 0.f, 0.f, 0.f};
    #pragma unroll
    for (int i = 0; i < 4; ++i)
        #pragma unroll
        for (int j = 0; j < 2; ++j) acc[i][j] = zero;

    const unsigned* Ab = Ap + (size_t)m0 * Kp;
    const unsigned* Bb = Wt + (size_t)n0 * Kp;

    const int g4 = lane >> 4;
    const int rr = lane & 15;

    auto STAGE = [&](int buf, int k0) {
        #pragma unroll
        for (int i = 0; i < 2; ++i) {
            int chunk = t + (i << 9);
            int row = chunk >> 3, ch = chunk & 7;
            int sch = ch ^ (row & 7);
            __builtin_amdgcn_global_load_lds(
                (const __attribute__((address_space(1))) unsigned*)(Ab + (size_t)row * Kp + k0 + (sch << 2)),
                &Au[buf][chunk << 2], 16, 0, 0);
        }
        #pragma unroll
        for (int i = 0; i < 2; ++i) {
            int chunk = t + (i << 9);
            int row = chunk >> 3, ch = chunk & 7;
            int sch = ch ^ (row & 7);
            __builtin_amdgcn_global_load_lds(
                (const __attribute__((address_space(1))) unsigned*)(Bb + (size_t)row * Kp + k0 + (sch << 2)),
                &Bu[buf][chunk << 2], 16, 0, 0);
        }
    };

    auto COMPUTE = [&](int buf) {
        const unsigned* au = Au[buf];
        const unsigned* bu = Bu[buf];
        short8 bh[2], bl[2];
        #pragma unroll
        for (int tj = 0; tj < 2; ++tj) {
            int r = wn * 32 + tj * 16 + rr;
            int c0 = (2 * g4) ^ (r & 7), c1 = (2 * g4 + 1) ^ (r & 7);
            uint4 p = *reinterpret_cast<const uint4*>(&bu[r * 32 + (c0 << 2)]);
            uint4 q = *reinterpret_cast<const uint4*>(&bu[r * 32 + (c1 << 2)]);
            union { short8 s; uint4 u; } H, L;
            H.u.x = __builtin_amdgcn_perm(p.y, p.x, 0x07060302u);
            L.u.x = __builtin_amdgcn_perm(p.y, p.x, 0x05040100u);
            H.u.y = __builtin_amdgcn_perm(p.w, p.z, 0x07060302u);
            L.u.y = __builtin_amdgcn_perm(p.w, p.z, 0x05040100u);
            H.u.z = __builtin_amdgcn_perm(q.y, q.x, 0x07060302u);
            L.u.z = __builtin_amdgcn_perm(q.y, q.x, 0x05040100u);
            H.u.w = __builtin_amdgcn_perm(q.w, q.z, 0x07060302u);
            L.u.w = __builtin_amdgcn_perm(q.w, q.z, 0x05040100u);
            bh[tj] = H.s; bl[tj] = L.s;
        }
        #pragma unroll
        for (int ti = 0; ti < 4; ++ti) {
            int r = wm * 64 + ti * 16 + rr;
            int c0 = (2 * g4) ^ (r & 7), c1 = (2 * g4 + 1) ^ (r & 7);
            uint4 p = *reinterpret_cast<const uint4*>(&au[r * 32 + (c0 << 2)]);
            uint4 q = *reinterpret_cast<const uint4*>(&au[r * 32 + (c1 << 2)]);
            union { short8 s; uint4 u; } H, L;
            H.u.x = __builtin_amdgcn_perm(p.y, p.x, 0x07060302u);
            L.u.x = __builtin_amdgcn_perm(p.y, p.x, 0x05040100u);
            H.u.y = __builtin_amdgcn_perm(p.w, p.z, 0x07060302u);
            L.u.y = __builtin_amdgcn_perm(p.w, p.z, 0x05040100u);
            H.u.z = __builtin_amdgcn_perm(q.y, q.x, 0x07060302u);
            L.u.z = __builtin_amdgcn_perm(q.y, q.x, 0x05040100u);
            H.u.w = __builtin_amdgcn_perm(q.w, q.z, 0x07060302u);
            L.u.w = __builtin_amdgcn_perm(q.w, q.z, 0x05040100u);
            short8 ah = H.s, al = L.s;
            #pragma unroll
            for (int tj = 0; tj < 2; ++tj) {
                f32x4 c = acc[ti][tj];
                c = __builtin_amdgcn_mfma_f32_16x16x32_bf16(ah, bh[tj], c, 0, 0, 0);
                c = __builtin_amdgcn_mfma_f32_16x16x32_bf16(ah, bl[tj], c, 0, 0, 0);
                c = __builtin_amdgcn_mfma_f32_16x16x32_bf16(al, bh[tj], c, 0, 0, 0);
                acc[ti][tj] = c;
            }
        }
    };

    const int nt = Kp >> 5;
    STAGE(0, 0);
    __syncthreads();
    int cur = 0;
    for (int ts = 0; ts < nt - 1; ++ts) {
        STAGE(cur ^ 1, (ts + 1) << 5);
        COMPUTE(cur);
        __syncthreads();
        cur ^= 1;
    }
    COMPUTE(cur);

    #pragma unroll
    for (int ti = 0; ti < 4; ++ti) {
        int row = m0 + wm * 64 + ti * 16 + (g4 << 2);
        #pragma unroll
        for (int tj = 0; tj < 2; ++tj) {
            int col = n0 + wn * 32 + tj * 16 + rr;
            float bv = bias[col];
            #pragma unroll
            for (int r = 0; r < 4; ++r) {
                float v = fmaxf(acc[ti][tj][r] + bv, 0.f);
                Cp[(size_t)(row + r) * N + col] = pack_split(v);
            }
        }
    }
}

// ONE WAVE PER (sample, bag): maximum memory-level parallelism for the
// random 512B row gather. No LDS (32 waves/CU), 10 independent row loads
// in flight per wave. Writes hi/lo-packed bag sums to bagp[s][f][128].
__global__ __launch_bounds__(256) void gather_bags(
    const int*   __restrict__ idx_words,
    const float* __restrict__ tables,
    unsigned*    __restrict__ bagp)
{
    __shared__ int sstride;
    const int t    = threadIdx.x;
    const int w    = t >> 6;
    const int lane = t & 63;
    const int g    = blockIdx.x * 4 + w;      // (sample, bag) pair id
    const int s    = g / F_;
    const int f    = g - s * F_;

    if (t == 0) {
        int st = 2;  // int64: odd (high) words all zero
        for (int ww = 1; ww < 256; ww += 2)
            if (idx_words[ww] != 0) { st = 1; break; }
        sstride = st;
    }
    __syncthreads();
    const int st = sstride;

    const float* tab = tables + (size_t)f * V_ * D_;
    const size_t ibase = (size_t)s * (F_ * L_) + (size_t)f * L_;
    float2 a = {0.f, 0.f};
    #pragma unroll
    for (int l = 0; l < L_; ++l) {
        int v = idx_words[(ibase + l) * st];
        v = v < 0 ? 0 : (v >= V_ ? V_ - 1 : v);
        float2 x = *reinterpret_cast<const float2*>(tab + (size_t)v * D_ + 2 * lane);
        a.x += x.x; a.y += x.y;
    }
    uint2 o;
    o.x = pack_split(a.x);
    o.y = pack_split(a.y);
    *reinterpret_cast<uint2*>(bagp + ((size_t)s * F_ + f) * 128 + 2 * lane) = o;
}

// 4 samples per block, one wave per sample: stream bagp rows + x2p into LDS
// hi/lo planes (XOR chunk-swizzled), 27x27 Gram via bf16x3 MFMA, write feats.
__global__ __launch_bounds__(256) void interact_mfma(
    const unsigned* __restrict__ x2p,      // [B,128] packed
    const unsigned* __restrict__ bagp,     // [B,26,128] packed
    unsigned*       __restrict__ featsp)   // [B,480] packed
{
    __shared__ unsigned zh[4][32][64];
    __shared__ unsigned zl[4][32][64];

    const int t    = threadIdx.x;
    const int w    = t >> 6;
    const int lane = t & 63;
    const int s    = blockIdx.x * 4 + w;   // sample

    uint2 xv = *reinterpret_cast<const uint2*>(x2p + (size_t)s * 128 + 2 * lane);
    *reinterpret_cast<uint2*>(featsp + (size_t)s * 480 + 2 * lane) = xv;
    if (lane == 0) featsp[(size_t)s * 480 + 479] = 0u;
    zh[w][0][lane] = (xv.x >> 16) | (xv.y & 0xFFFF0000u);
    zl[w][0][lane] = (xv.x & 0xFFFFu) | (xv.y << 16);

    for (int f = 0; f < F_; ++f) {
        uint2 u = *reinterpret_cast<const uint2*>(bagp + ((size_t)s * F_ + f) * 128 + 2 * lane);
        int r  = f + 1;
        int dw = (((lane >> 2) ^ (r & 7)) << 2) + (lane & 3);  // chunk-swizzled dword
        zh[w][r][dw] = (u.x >> 16) | (u.y & 0xFFFF0000u);
        zl[w][r][dw] = (u.x & 0xFFFFu) | (u.y << 16);
    }
    __syncthreads();

    const int g4 = lane >> 4;
    const int rr = lane & 15;
    f32x4 acc[2][2];
    const f32x4 zero = {0.f, 0.f, 0.f, 0.f};
    acc[0][0] = zero; acc[0][1] = zero; acc[1][0] = zero; acc[1][1] = zero;

    #pragma unroll
    for (int ks = 0; ks < 4; ++ks) {
        short8 h[2], lo[2];
        #pragma unroll
        for (int mi = 0; mi < 2; ++mi) {
            int r = mi * 16 + rr;
            int c = (ks * 4 + g4) ^ (r & 7);
            h[mi]  = *reinterpret_cast<const short8*>(&zh[w][r][c << 2]);
            lo[mi] = *reinterpret_cast<const short8*>(&zl[w][r][c << 2]);
        }
        #pragma unroll
        for (int mi = 0; mi < 2; ++mi)
            #pragma unroll
            for (int nj = 0; nj < 2; ++nj) {
                f32x4 c = acc[mi][nj];
                c = __builtin_amdgcn_mfma_f32_16x16x32_bf16(h[mi],  h[nj],  c, 0, 0, 0);
                c = __builtin_amdgcn_mfma_f32_16x16x32_bf16(h[mi],  lo[nj], c, 0, 0, 0);
                c = __builtin_amdgcn_mfma_f32_16x16x32_bf16(lo[mi], h[nj],  c, 0, 0, 0);
                acc[mi][nj] = c;
            }
    }

    #pragma unroll
    for (int mi = 0; mi < 2; ++mi) {
        #pragma unroll
        for (int nj = 0; nj < 2; ++nj) {
            #pragma unroll
            for (int r = 0; r < 4; ++r) {
                int i = mi * 16 + g4 * 4 + r;
                int j = nj * 16 + rr;
                if (i < j && j <= 26) {
                    int p = i * 26 - (i * (i - 1)) / 2 + (j - i - 1);
                    featsp[(size_t)s * 480 + 128 + p] = pack_split(acc[mi][nj][r]);
                }
            }
        }
    }
}

// logits[b] = dot(unpack(y3p[b,:256]), w) + bias
__global__ __launch_bounds__(256) void final_dot(
    const unsigned* __restrict__ yp, const float* __restrict__ w,
    const float* __restrict__ bias, float* __restrict__ out)
{
    const int wave = threadIdx.x >> 6;
    const int lane = threadIdx.x & 63;
    const int b = blockIdx.x * 4 + wave;
    uint4 u = *reinterpret_cast<const uint4*>(yp + (size_t)b * 256 + lane * 4);
    float4 wv = *reinterpret_cast<const float4*>(&w[lane * 4]);
    float s = unpack_f(u.x) * wv.x + unpack_f(u.y) * wv.y +
              unpack_f(u.z) * wv.z + unpack_f(u.w) * wv.w;
    #pragma unroll
    for (int off = 32; off; off >>= 1) s += __shfl_xor(s, off);
    if (lane == 0) out[b] = s + bias[0];
}

extern "C" void kernel_launch(void* const* d_in, const int* in_sizes, int n_in,
                              void* d_out, int out_size, void* d_ws, size_t ws_size,
                              hipStream_t stream)
{
    const float* dense   = (const float*)d_in[0];
    const int*   indices = (const int*)  d_in[1];
    const float* tables  = (const float*)d_in[2];
    const float* dW0 = (const float*)d_in[3];  const float* db0 = (const float*)d_in[4];
    const float* dW1 = (const float*)d_in[5];  const float* db1 = (const float*)d_in[6];
    const float* dW2 = (const float*)d_in[7];  const float* db2 = (const float*)d_in[8];
    const float* oW0 = (const float*)d_in[9];  const float* ob0 = (const float*)d_in[10];
    const float* oW1 = (const float*)d_in[11]; const float* ob1 = (const float*)d_in[12];
    const float* oW2 = (const float*)d_in[13]; const float* ob2 = (const float*)d_in[14];
    const float* oW3 = (const float*)d_in[15]; const float* ob3 = (const float*)d_in[16];
    const float* oW4 = (const float*)d_in[17]; const float* ob4 = (const float*)d_in[18];
    float* out = (float*)d_out;

    unsigned* wsu = (unsigned*)d_ws;
    unsigned* dWt0 = wsu + 0;          // [512][32]
    unsigned* dWt1 = wsu + 16384;      // [256][512]
    unsigned* dWt2 = wsu + 147456;     // [128][256]
    unsigned* oWt0 = wsu + 180224;     // [1024][480]
    unsigned* oWt1 = wsu + 671744;     // [1024][1024]
    unsigned* oWt2 = wsu + 1720320;    // [512][1024]
    unsigned* oWt3 = wsu + 2244608;    // [256][512]
    unsigned* densep = wsu + 2375680;  // [4096][32]
    unsigned* x2p    = wsu + 2506752;  // [4096][128]
    unsigned* featsp = wsu + 3031040;  // [4096][480]
    unsigned* x0p    = wsu + 5000000;  // [4096][512]
    unsigned* x1p    = wsu + 7097152;  // [4096][256]
    unsigned* y0p    = wsu + 5000000;  // [4096][1024] (x0p/x1p dead)
    unsigned* y1p    = wsu + 9194304;  // [4096][1024]
    unsigned* y2p    = wsu + 2506752;  // [4096][512]  (x2p/featsp dead)
    unsigned* y3p    = wsu + 5000000;  // [4096][256]  (y0p dead)
    unsigned* bagp   = wsu + 13500000; // [4096][26][128] = 13,631,488 uints
    // high water ~108.5 MB (d_ws poison fill shows 5.2 GB)

    // independent longest-pole first
    gather_bags<<<(B_ * F_) / 4, 256, 0, stream>>>(indices, tables, bagp);

    prep_all<<<2832, 256, 0, stream>>>(dW0, dW1, dW2, oW0, oW1, oW2, oW3,
                                       dWt0, dWt1, dWt2, oWt0, oWt1, oWt2, oWt3,
                                       dense, densep);

    gemm8<<<dim3(4, 32), 512, 0, stream>>>(densep, dWt0, db0, x0p, 512, 32);
    gemm8<<<dim3(2, 32), 512, 0, stream>>>(x0p,    dWt1, db1, x1p, 256, 512);
    gemm8<<<dim3(1, 32), 512, 0, stream>>>(x1p,    dWt2, db2, x2p, 128, 256);

    interact_mfma<<<B_ / 4, 256, 0, stream>>>(x2p, bagp, featsp);

    gemm8<<<dim3(8, 32), 512, 0, stream>>>(featsp, oWt0, ob0, y0p, 1024, 480);
    gemm8<<<dim3(8, 32), 512, 0, stream>>>(y0p,    oWt1, ob1, y1p, 1024, 1024);
    gemm8<<<dim3(4, 32), 512, 0, stream>>>(y1p,    oWt2, ob2, y2p, 512, 1024);
    gemm8<<<dim3(2, 32), 512, 0, stream>>>(y2p,    oWt3, ob3, y3p, 256, 512);

    final_dot<<<B_ / 4, 256, 0, stream>>>(y3p, oW4, ob4, out);
}